// Round 2
// baseline (162.548 us; speedup 1.0000x reference)
//
#include <hip/hip_runtime.h>
#include <math.h>

#define MIN_NORM 1e-15f
#define BOUND_EPS 1e-5f
#define TILE_K 16

__device__ __forceinline__ float wred64(float v) {
#pragma unroll
  for (int off = 32; off > 0; off >>= 1) v += __shfl_xor(v, off, 64);
  return v;
}

__device__ __forceinline__ float artanh_c(float x) {
  x = fminf(fmaxf(x, -1.f + BOUND_EPS), 1.f - BOUND_EPS);
  return 0.5f * logf((1.f + x) / (1.f - x));
}

// dist contribution for one row: x = this lane's component of the fixed vector,
// x2 = ||x||^2 (wave-uniform), y = this lane's component of res, y2 = ||y||^2.
__device__ __forceinline__ float dist_one(float x, float x2, float y, float y2) {
  float xy = -wred64(x * y);                      // sum((-x) * y)
  float A = 1.f + 2.f * xy + y2;
  float Bc = 1.f - x2;
  float num = Bc * y - A * x;                     // A*(-x) + Bc*y
  float den = fmaxf(1.f + 2.f * xy + x2 * y2, MIN_NORM);
  float v = num / den;
  float nv = fmaxf(sqrtf(wred64(v * v)), MIN_NORM);
  return 2.f * artanh_c(nv);
}

__global__ __launch_bounds__(256) void poincare_main(
    const float* __restrict__ seq, const float* __restrict__ proj,
    const float* __restrict__ trans, const float* __restrict__ pos,
    const float* __restrict__ neg, float* __restrict__ ws) {
  __shared__ float As[TILE_K][68];   // [kk][row]
  __shared__ float Bs[TILE_K][68];   // [kk][d]
  __shared__ float T[64][68];        // row-major tile: t, then te, then mx
  __shared__ float transL[64][68];   // [d][d'] = trans[d'][d]  (transposed)
  __shared__ float xnBuf[64];
  __shared__ float posL[64];
  __shared__ float negL[64];
  __shared__ float partial[4][2];

  const int tid = threadIdx.x;
  const int bIdx = blockIdx.x;
  const long r0 = (long)bIdx * 64;

  // Preload trans (transposed into [d][d']), pos, neg.
  for (int idx = tid; idx < 4096; idx += 256) {
    int dp = idx >> 6, dd = idx & 63;
    transL[dd][dp] = trans[idx];
  }
  if (tid < 64) posL[tid] = pos[tid];
  else if (tid < 128) negL[tid - 64] = neg[tid - 64];

  const int tx = tid & 15, ty = tid >> 4;

  float acc[4][4];
#pragma unroll
  for (int i = 0; i < 4; ++i)
#pragma unroll
    for (int j = 0; j < 4; ++j) acc[i][j] = 0.f;

  // ---- Phase 1: t = seq_rows @ proj  (M=64 rows, N=64, K=768) ----
  const int kk4 = (tid & 3) * 4;   // A-load: k sub-offset
  const int ra = tid >> 2;         // A-load: row 0..63
  const int d4 = (tid & 15) * 4;   // B-load: col
  const int kb = tid >> 4;         // B-load: k row 0..15

  for (int k0 = 0; k0 < 768; k0 += TILE_K) {
    float4 av = *(const float4*)(seq + (r0 + ra) * 768 + (k0 + kk4));
    float4 bv = *(const float4*)(proj + (long)(k0 + kb) * 64 + d4);
    __syncthreads();  // previous iteration's compute finished
    As[kk4 + 0][ra] = av.x;
    As[kk4 + 1][ra] = av.y;
    As[kk4 + 2][ra] = av.z;
    As[kk4 + 3][ra] = av.w;
    *(float4*)&Bs[kb][d4] = bv;
    __syncthreads();
#pragma unroll
    for (int kk = 0; kk < TILE_K; ++kk) {
      float4 a = *(const float4*)&As[kk][ty * 4];
      float4 b = *(const float4*)&Bs[kk][tx * 4];
      float a_[4] = {a.x, a.y, a.z, a.w};
      float b_[4] = {b.x, b.y, b.z, b.w};
#pragma unroll
      for (int i = 0; i < 4; ++i)
#pragma unroll
        for (int j = 0; j < 4; ++j) acc[i][j] += a_[i] * b_[j];
    }
  }

  // write t tile to LDS
#pragma unroll
  for (int i = 0; i < 4; ++i) {
    float4 o = make_float4(acc[i][0], acc[i][1], acc[i][2], acc[i][3]);
    *(float4*)&T[ty * 4 + i][tx * 4] = o;
  }
  __syncthreads();

  // ---- Phase 2a: expmap0 per row (wave w owns rows w*16..w*16+15) ----
  const int w = tid >> 6, lane = tid & 63;
  for (int i = 0; i < 16; ++i) {
    int row = w * 16 + i;
    float u = T[row][lane];
    float n = fmaxf(sqrtf(wred64(u * u)), MIN_NORM);
    float th = tanhf(n);
    T[row][lane] = th / n * u;  // te
    if (lane == 0) xnBuf[row] = fmaxf(th, MIN_NORM);  // xn = ||te||
  }
  __syncthreads();

  // ---- Phase 2b: mx = te_tile @ trans^T  (64x64x64) ----
  float acc2[4][4];
#pragma unroll
  for (int i = 0; i < 4; ++i)
#pragma unroll
    for (int j = 0; j < 4; ++j) acc2[i][j] = 0.f;
#pragma unroll 4
  for (int d = 0; d < 64; ++d) {
    float a_[4];
#pragma unroll
    for (int i = 0; i < 4; ++i) a_[i] = T[ty * 4 + i][d];
    float4 b = *(const float4*)&transL[d][tx * 4];
    float b_[4] = {b.x, b.y, b.z, b.w};
#pragma unroll
    for (int i = 0; i < 4; ++i)
#pragma unroll
      for (int j = 0; j < 4; ++j) acc2[i][j] += a_[i] * b_[j];
  }
  __syncthreads();  // all reads of te done before overwrite
#pragma unroll
  for (int i = 0; i < 4; ++i) {
    float4 o = make_float4(acc2[i][0], acc2[i][1], acc2[i][2], acc2[i][3]);
    *(float4*)&T[ty * 4 + i][tx * 4] = o;  // T now holds mx
  }
  __syncthreads();

  // ---- Phase 2c: mobius_matvec epilogue + dists ----
  float xp = posL[lane], xq = negL[lane];
  float x2p = wred64(xp * xp);
  float x2n = wred64(xq * xq);
  float distP = 0.f, distN = 0.f;
  for (int i = 0; i < 16; ++i) {
    int row = w * 16 + i;
    float mx = T[row][lane];
    float xn = xnBuf[row];
    float mxn = fmaxf(sqrtf(wred64(mx * mx)), MIN_NORM);
    float res = tanhf(mxn / xn * artanh_c(xn)) / mxn * mx;
    float y2 = wred64(res * res);
    distP += dist_one(xp, x2p, res, y2);
    distN += dist_one(xq, x2n, res, y2);
  }
  if (lane == 0) {
    partial[w][0] = distP;
    partial[w][1] = distN;
  }
  __syncthreads();
  if (tid == 0) {
    ws[bIdx * 2 + 0] = partial[0][0] + partial[1][0] + partial[2][0] + partial[3][0];
    ws[bIdx * 2 + 1] = partial[0][1] + partial[1][1] + partial[2][1] + partial[3][1];
  }
}

// Deterministic per-batch reduction: out[b][j] = sum over the batch's 16 blocks.
__global__ __launch_bounds__(128) void poincare_reduce(const float* __restrict__ ws,
                                                       float* __restrict__ out) {
  int t = threadIdx.x;  // 0..127
  int b = t >> 1, j = t & 1;
  float s = 0.f;
#pragma unroll
  for (int i = 0; i < 16; ++i) s += ws[(b * 16 + i) * 2 + j];
  out[b * 2 + j] = s;
}

extern "C" void kernel_launch(void* const* d_in, const int* in_sizes, int n_in,
                              void* d_out, int out_size, void* d_ws, size_t ws_size,
                              hipStream_t stream) {
  const float* seq = (const float*)d_in[0];
  const float* proj = (const float*)d_in[1];
  const float* trans = (const float*)d_in[2];
  const float* pos = (const float*)d_in[3];
  const float* neg = (const float*)d_in[4];
  float* ws = (float*)d_ws;
  float* out = (float*)d_out;

  poincare_main<<<1024, 256, 0, stream>>>(seq, proj, trans, pos, neg, ws);
  poincare_reduce<<<1, 128, 0, stream>>>(ws, out);
}

// Round 3
// 54.808 us; speedup vs baseline: 2.9658x; 2.9658x over previous
//
#include <hip/hip_runtime.h>
#include <math.h>

#define MIN_NORM 1e-15f
#define BOUND_EPS 1e-5f

typedef __attribute__((ext_vector_type(8))) short short8v;
typedef __attribute__((ext_vector_type(4))) float f32x4;

__device__ __forceinline__ unsigned short f2bf(float f) {
  unsigned int u = __float_as_uint(f);
  unsigned int r = (u + 0x7FFFu + ((u >> 16) & 1u)) >> 16;  // RNE
  return (unsigned short)r;
}

__device__ __forceinline__ float gred16(float v) {  // reduce within aligned 16-lane group
  v += __shfl_xor(v, 1, 64);
  v += __shfl_xor(v, 2, 64);
  v += __shfl_xor(v, 4, 64);
  v += __shfl_xor(v, 8, 64);
  return v;
}
__device__ __forceinline__ float wred64(float v) {
#pragma unroll
  for (int off = 32; off; off >>= 1) v += __shfl_xor(v, off, 64);
  return v;
}
__device__ __forceinline__ float artanh_c(float x) {
  x = fminf(fmaxf(x, -1.f + BOUND_EPS), 1.f - BOUND_EPS);
  return 0.5f * logf((1.f + x) / (1.f - x));
}

// Repack proj -> B-fragment order (bf16) and trans -> B-frag order for te @ trans^T.
// projB[((kt*4+nt)*64+l)*8+j] = proj[kt*32+(l>>4)*8+j][nt*16+(l&15)], kt=0..23
// transB[((kt*4+nt)*64+l)*8+j] = trans[nt*16+(l&15)][kt*32+(l>>4)*8+j], kt=0..1
__global__ __launch_bounds__(256) void poincare_prep(
    const float* __restrict__ proj, const float* __restrict__ trans,
    unsigned short* __restrict__ projB, unsigned short* __restrict__ transB) {
  int idx = blockIdx.x * 256 + threadIdx.x;
  if (idx < 49152) {
    int j = idx & 7, l = (idx >> 3) & 63, nt = (idx >> 9) & 3, kt = idx >> 11;
    projB[idx] = f2bf(proj[(kt * 32 + (l >> 4) * 8 + j) * 64 + nt * 16 + (l & 15)]);
  } else if (idx < 49152 + 4096) {
    int i2 = idx - 49152;
    int j = i2 & 7, l = (i2 >> 3) & 63, nt = (i2 >> 9) & 3, kt = i2 >> 11;
    transB[i2] = f2bf(trans[(nt * 16 + (l & 15)) * 64 + kt * 32 + (l >> 4) * 8 + j]);
  }
}

__global__ __launch_bounds__(256, 4) void poincare_main(
    const float* __restrict__ seq,
    const unsigned short* __restrict__ projB,
    const unsigned short* __restrict__ transB,
    const float* __restrict__ pos, const float* __restrict__ neg,
    float* __restrict__ wsPart) {
  __shared__ unsigned short teL[4][16 * 64];  // per-wave 2KB transpose buffer
  __shared__ float partial[4][2];

  const int tid = threadIdx.x;
  const int w = tid >> 6, l = tid & 63;
  const int lr = l & 15, lk = l >> 4;  // frag row(M/N index) / k-group
  const long bIdx = blockIdx.x;

  // ---- Phase 1: t = seq_rows @ proj (per wave: 16 rows x 64 cols, K=768) ----
  const float* pA = seq + ((bIdx * 64 + w * 16 + lr) * 768 + lk * 8);
  const unsigned short* pB = projB + l * 8;

  f32x4 acc[4];
#pragma unroll
  for (int nt = 0; nt < 4; ++nt) acc[nt] = (f32x4){0.f, 0.f, 0.f, 0.f};

  for (int kt = 0; kt < 24; ++kt) {
    float4 a0 = *(const float4*)(pA);
    float4 a1 = *(const float4*)(pA + 4);
    pA += 32;
    const unsigned short* pb = pB + kt * 2048;
    short8v b0 = *(const short8v*)(pb);
    short8v b1 = *(const short8v*)(pb + 512);
    short8v b2 = *(const short8v*)(pb + 1024);
    short8v b3 = *(const short8v*)(pb + 1536);
    short8v av;
    av[0] = (short)f2bf(a0.x); av[1] = (short)f2bf(a0.y);
    av[2] = (short)f2bf(a0.z); av[3] = (short)f2bf(a0.w);
    av[4] = (short)f2bf(a1.x); av[5] = (short)f2bf(a1.y);
    av[6] = (short)f2bf(a1.z); av[7] = (short)f2bf(a1.w);
    acc[0] = __builtin_amdgcn_mfma_f32_16x16x32_bf16(av, b0, acc[0], 0, 0, 0);
    acc[1] = __builtin_amdgcn_mfma_f32_16x16x32_bf16(av, b1, acc[1], 0, 0, 0);
    acc[2] = __builtin_amdgcn_mfma_f32_16x16x32_bf16(av, b2, acc[2], 0, 0, 0);
    acc[3] = __builtin_amdgcn_mfma_f32_16x16x32_bf16(av, b3, acc[3], 0, 0, 0);
  }

  // C layout: col = nt*16 + (l&15), row = lk*4 + i (i = reg). Row-local group = 16 lanes.
  // ---- Phase 2a: expmap0 in-register ----
  float th[4];
#pragma unroll
  for (int i = 0; i < 4; ++i) {
    float s = acc[0][i] * acc[0][i] + acc[1][i] * acc[1][i] +
              acc[2][i] * acc[2][i] + acc[3][i] * acc[3][i];
    s = gred16(s);
    float n = fmaxf(sqrtf(s), MIN_NORM);
    float t = tanhf(n);
    th[i] = fmaxf(t, MIN_NORM);  // xn = ||te||
    float sc = t / n;
#pragma unroll
    for (int nt = 0; nt < 4; ++nt) acc[nt][i] *= sc;  // te
  }

  // ---- te: C-layout -> A-frag layout via wave-private LDS (XOR-swizzled, G4) ----
  unsigned short* buf = teL[w];
#pragma unroll
  for (int i = 0; i < 4; ++i) {
    int row = lk * 4 + i;
    int sw = (row & 7) << 3;
#pragma unroll
    for (int nt = 0; nt < 4; ++nt) {
      int col = nt * 16 + lr;
      buf[row * 64 + (col ^ sw)] = f2bf(acc[nt][i]);
    }
  }
  __syncthreads();

  // ---- Phase 2b: mx = te @ trans^T (K=64) ----
  f32x4 acc2[4];
#pragma unroll
  for (int nt = 0; nt < 4; ++nt) acc2[nt] = (f32x4){0.f, 0.f, 0.f, 0.f};
  const unsigned short* pT = transB + l * 8;
#pragma unroll
  for (int kt = 0; kt < 2; ++kt) {
    short8v a2 = *(const short8v*)&buf[lr * 64 + ((kt * 32 + lk * 8) ^ ((lr & 7) << 3))];
    const unsigned short* pt = pT + kt * 2048;
    short8v c0 = *(const short8v*)(pt);
    short8v c1 = *(const short8v*)(pt + 512);
    short8v c2 = *(const short8v*)(pt + 1024);
    short8v c3 = *(const short8v*)(pt + 1536);
    acc2[0] = __builtin_amdgcn_mfma_f32_16x16x32_bf16(a2, c0, acc2[0], 0, 0, 0);
    acc2[1] = __builtin_amdgcn_mfma_f32_16x16x32_bf16(a2, c1, acc2[1], 0, 0, 0);
    acc2[2] = __builtin_amdgcn_mfma_f32_16x16x32_bf16(a2, c2, acc2[2], 0, 0, 0);
    acc2[3] = __builtin_amdgcn_mfma_f32_16x16x32_bf16(a2, c3, acc2[3], 0, 0, 0);
  }

  // ---- Phase 2c: mobius_matvec epilogue + dists, fully in-register ----
  float xp[4], xq[4];
#pragma unroll
  for (int nt = 0; nt < 4; ++nt) {
    xp[nt] = pos[nt * 16 + lr];
    xq[nt] = neg[nt * 16 + lr];
  }
  float x2p = wred64(xp[0] * xp[0] + xp[1] * xp[1] + xp[2] * xp[2] + xp[3] * xp[3]) * 0.25f;
  float x2n = wred64(xq[0] * xq[0] + xq[1] * xq[1] + xq[2] * xq[2] + xq[3] * xq[3]) * 0.25f;

  float distP = 0.f, distN = 0.f;
#pragma unroll
  for (int i = 0; i < 4; ++i) {
    float m0 = acc2[0][i], m1 = acc2[1][i], m2 = acc2[2][i], m3 = acc2[3][i];
    float s = gred16(m0 * m0 + m1 * m1 + m2 * m2 + m3 * m3);
    float mxn = fmaxf(sqrtf(s), MIN_NORM);
    float xn = th[i];
    float rs = tanhf(mxn / xn * artanh_c(xn)) / mxn;
    float r0 = rs * m0, r1 = rs * m1, r2 = rs * m2, r3 = rs * m3;
    float y2 = gred16(r0 * r0 + r1 * r1 + r2 * r2 + r3 * r3);
    float xyP = -gred16(xp[0] * r0 + xp[1] * r1 + xp[2] * r2 + xp[3] * r3);
    float xyN = -gred16(xq[0] * r0 + xq[1] * r1 + xq[2] * r2 + xq[3] * r3);
    {
      float A = 1.f + 2.f * xyP + y2, B = 1.f - x2p;
      float inv = 1.f / fmaxf(1.f + 2.f * xyP + x2p * y2, MIN_NORM);
      float v0 = (B * r0 - A * xp[0]) * inv, v1 = (B * r1 - A * xp[1]) * inv;
      float v2 = (B * r2 - A * xp[2]) * inv, v3 = (B * r3 - A * xp[3]) * inv;
      float nv = fmaxf(sqrtf(gred16(v0 * v0 + v1 * v1 + v2 * v2 + v3 * v3)), MIN_NORM);
      distP += 2.f * artanh_c(nv);
    }
    {
      float A = 1.f + 2.f * xyN + y2, B = 1.f - x2n;
      float inv = 1.f / fmaxf(1.f + 2.f * xyN + x2n * y2, MIN_NORM);
      float v0 = (B * r0 - A * xq[0]) * inv, v1 = (B * r1 - A * xq[1]) * inv;
      float v2 = (B * r2 - A * xq[2]) * inv, v3 = (B * r3 - A * xq[3]) * inv;
      float nv = fmaxf(sqrtf(gred16(v0 * v0 + v1 * v1 + v2 * v2 + v3 * v3)), MIN_NORM);
      distN += 2.f * artanh_c(nv);
    }
  }
  // Each group's dist is replicated on its 16 lanes: wred64/16 sums groups once.
  float tP = wred64(distP) * 0.0625f;
  float tN = wred64(distN) * 0.0625f;
  if (l == 0) { partial[w][0] = tP; partial[w][1] = tN; }
  __syncthreads();
  if (tid == 0)
    wsPart[bIdx * 2 + 0] = partial[0][0] + partial[1][0] + partial[2][0] + partial[3][0];
  if (tid == 1)
    wsPart[bIdx * 2 + 1] = partial[0][1] + partial[1][1] + partial[2][1] + partial[3][1];
}

__global__ __launch_bounds__(128) void poincare_reduce(const float* __restrict__ wsPart,
                                                       float* __restrict__ out) {
  int t = threadIdx.x;
  int b = t >> 1, j = t & 1;
  float s = 0.f;
#pragma unroll
  for (int i = 0; i < 16; ++i) s += wsPart[(b * 16 + i) * 2 + j];
  out[b * 2 + j] = s;
}

extern "C" void kernel_launch(void* const* d_in, const int* in_sizes, int n_in,
                              void* d_out, int out_size, void* d_ws, size_t ws_size,
                              hipStream_t stream) {
  const float* seq = (const float*)d_in[0];
  const float* proj = (const float*)d_in[1];
  const float* trans = (const float*)d_in[2];
  const float* pos = (const float*)d_in[3];
  const float* neg = (const float*)d_in[4];

  unsigned short* projB = (unsigned short*)d_ws;            // 49152 u16 = 98304 B
  unsigned short* transB = projB + 49152;                   // 4096 u16  = 8192 B
  float* wsPart = (float*)((char*)d_ws + 106496);           // 2048 f32  = 8192 B
  float* out = (float*)d_out;

  poincare_prep<<<208, 256, 0, stream>>>(proj, trans, projB, transB);
  poincare_main<<<1024, 256, 0, stream>>>(seq, projB, transB, pos, neg, wsPart);
  poincare_reduce<<<1, 128, 0, stream>>>(wsPart, out);
}

// Round 5
// 54.166 us; speedup vs baseline: 3.0009x; 1.0119x over previous
//
#include <hip/hip_runtime.h>
#include <math.h>

#define MIN_NORM 1e-15f
#define BOUND_EPS 1e-5f

typedef __attribute__((ext_vector_type(8))) short short8v;
typedef __attribute__((ext_vector_type(4))) float f32x4;

__device__ __forceinline__ unsigned short f2bf(float f) {
  unsigned int u = __float_as_uint(f);
  unsigned int r = (u + 0x7FFFu + ((u >> 16) & 1u)) >> 16;  // RNE
  return (unsigned short)r;
}

__device__ __forceinline__ float gred16(float v) {  // reduce within aligned 16-lane group
  v += __shfl_xor(v, 1, 64);
  v += __shfl_xor(v, 2, 64);
  v += __shfl_xor(v, 4, 64);
  v += __shfl_xor(v, 8, 64);
  return v;
}
__device__ __forceinline__ float wred64(float v) {
#pragma unroll
  for (int off = 32; off; off >>= 1) v += __shfl_xor(v, off, 64);
  return v;
}
__device__ __forceinline__ float artanh_c(float x) {
  x = fminf(fmaxf(x, -1.f + BOUND_EPS), 1.f - BOUND_EPS);
  return 0.5f * logf((1.f + x) / (1.f - x));
}

// Repack proj -> B-fragment order (bf16) and trans -> B-frag order for te @ trans^T.
// projB[((kt*4+nt)*64+l)*8+j] = proj[kt*32+(l>>4)*8+j][nt*16+(l&15)], kt=0..23
// transB[((kt*4+nt)*64+l)*8+j] = trans[nt*16+(l&15)][kt*32+(l>>4)*8+j], kt=0..1
__global__ __launch_bounds__(256) void poincare_prep(
    const float* __restrict__ proj, const float* __restrict__ trans,
    unsigned short* __restrict__ projB, unsigned short* __restrict__ transB) {
  int idx = blockIdx.x * 256 + threadIdx.x;
  if (idx < 49152) {
    int j = idx & 7, l = (idx >> 3) & 63, nt = (idx >> 9) & 3, kt = idx >> 11;
    projB[idx] = f2bf(proj[(kt * 32 + (l >> 4) * 8 + j) * 64 + nt * 16 + (l & 15)]);
  } else if (idx < 49152 + 4096) {
    int i2 = idx - 49152;
    int j = i2 & 7, l = (i2 >> 3) & 63, nt = (i2 >> 9) & 3, kt = i2 >> 11;
    transB[i2] = f2bf(trans[(nt * 16 + (l & 15)) * 64 + kt * 32 + (l >> 4) * 8 + j]);
  }
}

__global__ __launch_bounds__(256, 4) void poincare_main(
    const float* __restrict__ seq,
    const unsigned short* __restrict__ projB,
    const unsigned short* __restrict__ transB,
    const float* __restrict__ pos, const float* __restrict__ neg,
    float* __restrict__ wsPart) {
  __shared__ unsigned short teL[4][16 * 64];  // per-wave 2KB transpose buffer
  __shared__ float partial[4][2];

  const int tid = threadIdx.x;
  const int w = tid >> 6, l = tid & 63;
  const int lr = l & 15, lk = l >> 4;  // frag row(M/N index) / k-group
  const long bIdx = blockIdx.x;

  // ---- Phase 1: t = seq_rows @ proj (per wave: 16 rows x 64 cols, K=768) ----
  const float* pA = seq + ((bIdx * 64 + w * 16 + lr) * 768 + lk * 8);
  const unsigned short* pB = projB + l * 8;

  f32x4 acc[4];
#pragma unroll
  for (int nt = 0; nt < 4; ++nt) acc[nt] = (f32x4){0.f, 0.f, 0.f, 0.f};

  // 2-stage register pipeline: loads for kt+1 issue before compute of kt.
  float4 a0 = *(const float4*)(pA);
  float4 a1 = *(const float4*)(pA + 4);
  short8v b0 = *(const short8v*)(pB);
  short8v b1 = *(const short8v*)(pB + 512);
  short8v b2 = *(const short8v*)(pB + 1024);
  short8v b3 = *(const short8v*)(pB + 1536);

  for (int kt = 0; kt < 24; ++kt) {
    float4 na0, na1;
    short8v nb0, nb1, nb2, nb3;
    if (kt < 23) {
      const float* p = pA + 32 * (kt + 1);
      na0 = *(const float4*)(p);
      na1 = *(const float4*)(p + 4);
      const unsigned short* pb = pB + (kt + 1) * 2048;
      nb0 = *(const short8v*)(pb);
      nb1 = *(const short8v*)(pb + 512);
      nb2 = *(const short8v*)(pb + 1024);
      nb3 = *(const short8v*)(pb + 1536);
    } else {
      na0 = a0; na1 = a1; nb0 = b0; nb1 = b1; nb2 = b2; nb3 = b3;
    }
    short8v av;
    av[0] = (short)f2bf(a0.x); av[1] = (short)f2bf(a0.y);
    av[2] = (short)f2bf(a0.z); av[3] = (short)f2bf(a0.w);
    av[4] = (short)f2bf(a1.x); av[5] = (short)f2bf(a1.y);
    av[6] = (short)f2bf(a1.z); av[7] = (short)f2bf(a1.w);
    acc[0] = __builtin_amdgcn_mfma_f32_16x16x32_bf16(av, b0, acc[0], 0, 0, 0);
    acc[1] = __builtin_amdgcn_mfma_f32_16x16x32_bf16(av, b1, acc[1], 0, 0, 0);
    acc[2] = __builtin_amdgcn_mfma_f32_16x16x32_bf16(av, b2, acc[2], 0, 0, 0);
    acc[3] = __builtin_amdgcn_mfma_f32_16x16x32_bf16(av, b3, acc[3], 0, 0, 0);
    a0 = na0; a1 = na1;
    b0 = nb0; b1 = nb1; b2 = nb2; b3 = nb3;
  }

  // C layout: col = nt*16 + (l&15), row = lk*4 + i (i = reg). Row-local group = 16 lanes.
  // ---- Phase 2a: expmap0 in-register ----
  float th[4];
#pragma unroll
  for (int i = 0; i < 4; ++i) {
    float s = acc[0][i] * acc[0][i] + acc[1][i] * acc[1][i] +
              acc[2][i] * acc[2][i] + acc[3][i] * acc[3][i];
    s = gred16(s);
    float n = fmaxf(sqrtf(s), MIN_NORM);
    float t = tanhf(n);
    th[i] = fmaxf(t, MIN_NORM);  // xn = ||te||
    float sc = t / n;
#pragma unroll
    for (int nt = 0; nt < 4; ++nt) acc[nt][i] *= sc;  // te
  }

  // ---- te: C-layout -> A-frag layout via wave-private LDS (XOR-swizzled, G4) ----
  unsigned short* buf = teL[w];
#pragma unroll
  for (int i = 0; i < 4; ++i) {
    int row = lk * 4 + i;
    int sw = (row & 7) << 3;
#pragma unroll
    for (int nt = 0; nt < 4; ++nt) {
      int col = nt * 16 + lr;
      buf[row * 64 + (col ^ sw)] = f2bf(acc[nt][i]);
    }
  }
  __syncthreads();

  // ---- Phase 2b: mx = te @ trans^T (K=64) ----
  f32x4 acc2[4];
#pragma unroll
  for (int nt = 0; nt < 4; ++nt) acc2[nt] = (f32x4){0.f, 0.f, 0.f, 0.f};
  const unsigned short* pT = transB + l * 8;
#pragma unroll
  for (int kt = 0; kt < 2; ++kt) {
    short8v a2 = *(const short8v*)&buf[lr * 64 + ((kt * 32 + lk * 8) ^ ((lr & 7) << 3))];
    const unsigned short* pt = pT + kt * 2048;
    short8v c0 = *(const short8v*)(pt);
    short8v c1 = *(const short8v*)(pt + 512);
    short8v c2 = *(const short8v*)(pt + 1024);
    short8v c3 = *(const short8v*)(pt + 1536);
    acc2[0] = __builtin_amdgcn_mfma_f32_16x16x32_bf16(a2, c0, acc2[0], 0, 0, 0);
    acc2[1] = __builtin_amdgcn_mfma_f32_16x16x32_bf16(a2, c1, acc2[1], 0, 0, 0);
    acc2[2] = __builtin_amdgcn_mfma_f32_16x16x32_bf16(a2, c2, acc2[2], 0, 0, 0);
    acc2[3] = __builtin_amdgcn_mfma_f32_16x16x32_bf16(a2, c3, acc2[3], 0, 0, 0);
  }

  // ---- Phase 2c: mobius_matvec epilogue + dists, fully in-register ----
  float xp[4], xq[4];
#pragma unroll
  for (int nt = 0; nt < 4; ++nt) {
    xp[nt] = pos[nt * 16 + lr];
    xq[nt] = neg[nt * 16 + lr];
  }
  float x2p = wred64(xp[0] * xp[0] + xp[1] * xp[1] + xp[2] * xp[2] + xp[3] * xp[3]) * 0.25f;
  float x2n = wred64(xq[0] * xq[0] + xq[1] * xq[1] + xq[2] * xq[2] + xq[3] * xq[3]) * 0.25f;

  float distP = 0.f, distN = 0.f;
#pragma unroll
  for (int i = 0; i < 4; ++i) {
    float m0 = acc2[0][i], m1 = acc2[1][i], m2 = acc2[2][i], m3 = acc2[3][i];
    float s = gred16(m0 * m0 + m1 * m1 + m2 * m2 + m3 * m3);
    float mxn = fmaxf(sqrtf(s), MIN_NORM);
    float xn = th[i];
    float rs = tanhf(mxn / xn * artanh_c(xn)) / mxn;
    float r0 = rs * m0, r1 = rs * m1, r2 = rs * m2, r3 = rs * m3;
    float y2 = gred16(r0 * r0 + r1 * r1 + r2 * r2 + r3 * r3);
    float xyP = -gred16(xp[0] * r0 + xp[1] * r1 + xp[2] * r2 + xp[3] * r3);
    float xyN = -gred16(xq[0] * r0 + xq[1] * r1 + xq[2] * r2 + xq[3] * r3);
    {
      float A = 1.f + 2.f * xyP + y2, B = 1.f - x2p;
      float inv = 1.f / fmaxf(1.f + 2.f * xyP + x2p * y2, MIN_NORM);
      float v0 = (B * r0 - A * xp[0]) * inv, v1 = (B * r1 - A * xp[1]) * inv;
      float v2 = (B * r2 - A * xp[2]) * inv, v3 = (B * r3 - A * xp[3]) * inv;
      float nv = fmaxf(sqrtf(gred16(v0 * v0 + v1 * v1 + v2 * v2 + v3 * v3)), MIN_NORM);
      distP += 2.f * artanh_c(nv);
    }
    {
      float A = 1.f + 2.f * xyN + y2, B = 1.f - x2n;
      float inv = 1.f / fmaxf(1.f + 2.f * xyN + x2n * y2, MIN_NORM);
      float v0 = (B * r0 - A * xq[0]) * inv, v1 = (B * r1 - A * xq[1]) * inv;
      float v2 = (B * r2 - A * xq[2]) * inv, v3 = (B * r3 - A * xq[3]) * inv;
      float nv = fmaxf(sqrtf(gred16(v0 * v0 + v1 * v1 + v2 * v2 + v3 * v3)), MIN_NORM);
      distN += 2.f * artanh_c(nv);
    }
  }
  // Each group's dist is replicated on its 16 lanes: wred64/16 sums groups once.
  float tP = wred64(distP) * 0.0625f;
  float tN = wred64(distN) * 0.0625f;
  if (l == 0) { partial[w][0] = tP; partial[w][1] = tN; }
  __syncthreads();
  if (tid == 0) {
    wsPart[bIdx * 2 + 0] = partial[0][0] + partial[1][0] + partial[2][0] + partial[3][0];
    wsPart[bIdx * 2 + 1] = partial[0][1] + partial[1][1] + partial[2][1] + partial[3][1];
  }
}

// Deterministic per-batch reduction: out[b][j] = sum over the batch's 16 blocks.
// Separate kernel => stream-ordered, no cross-XCD visibility hazard (G16).
__global__ __launch_bounds__(128) void poincare_reduce(const float* __restrict__ wsPart,
                                                       float* __restrict__ out) {
  int t = threadIdx.x;
  int b = t >> 1, j = t & 1;
  float s = 0.f;
#pragma unroll
  for (int i = 0; i < 16; ++i) s += wsPart[(b * 16 + i) * 2 + j];
  out[b * 2 + j] = s;
}

extern "C" void kernel_launch(void* const* d_in, const int* in_sizes, int n_in,
                              void* d_out, int out_size, void* d_ws, size_t ws_size,
                              hipStream_t stream) {
  const float* seq = (const float*)d_in[0];
  const float* proj = (const float*)d_in[1];
  const float* trans = (const float*)d_in[2];
  const float* pos = (const float*)d_in[3];
  const float* neg = (const float*)d_in[4];

  unsigned short* projB = (unsigned short*)d_ws;             // 49152 u16 = 98304 B
  unsigned short* transB = projB + 49152;                    // 4096 u16  = 8192 B
  float* wsPart = (float*)((char*)d_ws + 106496);            // 2048 f32  = 8192 B
  float* out = (float*)d_out;

  poincare_prep<<<208, 256, 0, stream>>>(proj, trans, projB, transB);
  poincare_main<<<1024, 256, 0, stream>>>(seq, projB, transB, pos, neg, wsPart);
  poincare_reduce<<<1, 128, 0, stream>>>(wsPart, out);
}

// Round 6
// 53.591 us; speedup vs baseline: 3.0331x; 1.0107x over previous
//
#include <hip/hip_runtime.h>
#include <math.h>

#define MIN_NORM 1e-15f
#define BOUND_EPS 1e-5f

typedef __attribute__((ext_vector_type(8))) short short8v;
typedef __attribute__((ext_vector_type(4))) float f32x4;

__device__ __forceinline__ unsigned short f2bf(float f) {
  unsigned int u = __float_as_uint(f);
  unsigned int r = (u + 0x7FFFu + ((u >> 16) & 1u)) >> 16;  // RNE
  return (unsigned short)r;
}

__device__ __forceinline__ float gred16(float v) {  // reduce within aligned 16-lane group
  v += __shfl_xor(v, 1, 64);
  v += __shfl_xor(v, 2, 64);
  v += __shfl_xor(v, 4, 64);
  v += __shfl_xor(v, 8, 64);
  return v;
}
__device__ __forceinline__ float wred64(float v) {
#pragma unroll
  for (int off = 32; off; off >>= 1) v += __shfl_xor(v, off, 64);
  return v;
}
__device__ __forceinline__ float artanh_c(float x) {
  x = fminf(fmaxf(x, -1.f + BOUND_EPS), 1.f - BOUND_EPS);
  return 0.5f * logf((1.f + x) / (1.f - x));
}

// Repack proj -> B-fragment order (bf16) and trans -> B-frag order for te @ trans^T.
// projB[((kt*4+nt)*64+l)*8+j] = proj[kt*32+(l>>4)*8+j][nt*16+(l&15)], kt=0..23
// transB[((kt*4+nt)*64+l)*8+j] = trans[nt*16+(l&15)][kt*32+(l>>4)*8+j], kt=0..1
__global__ __launch_bounds__(256) void poincare_prep(
    const float* __restrict__ proj, const float* __restrict__ trans,
    unsigned short* __restrict__ projB, unsigned short* __restrict__ transB) {
  int idx = blockIdx.x * 256 + threadIdx.x;
  if (idx < 49152) {
    int j = idx & 7, l = (idx >> 3) & 63, nt = (idx >> 9) & 3, kt = idx >> 11;
    projB[idx] = f2bf(proj[(kt * 32 + (l >> 4) * 8 + j) * 64 + nt * 16 + (l & 15)]);
  } else if (idx < 49152 + 4096) {
    int i2 = idx - 49152;
    int j = i2 & 7, l = (i2 >> 3) & 63, nt = (i2 >> 9) & 3, kt = i2 >> 11;
    transB[i2] = f2bf(trans[(nt * 16 + (l & 15)) * 64 + kt * 32 + (l >> 4) * 8 + j]);
  }
}

// 512 threads = 8 waves. Wave w: pair p = w&3 (rows p*16..p*16+15 of the block's
// 64 rows), half h = w>>2 (K-tiles h*12..h*12+11). K-split doubles resident waves
// (8192 total = 8 waves/SIMD); __launch_bounds__(512,8) caps VGPRs at 64 so they fit.
__global__ __launch_bounds__(512, 8) void poincare_main(
    const float* __restrict__ seq,
    const unsigned short* __restrict__ projB,
    const unsigned short* __restrict__ transB,
    const float* __restrict__ pos, const float* __restrict__ neg,
    float* __restrict__ wsPart) {
  __shared__ unsigned short teL[4][16 * 64];  // per-pair 2KB transpose buffer
  __shared__ float xbuf[4][64][17];           // K-split combine (+1 pad: bank-free)
  __shared__ float partial[4][2];

  const int tid = threadIdx.x;
  const int w = tid >> 6, l = tid & 63;
  const int p = w & 3, h = w >> 2;
  const int lr = l & 15, lk = l >> 4;  // frag row(M/N index) / k-group
  const long bIdx = blockIdx.x;

  // ---- Phase 1: t = seq_rows @ proj; this wave does 12 of 24 K-tiles ----
  const float* pA = seq + ((bIdx * 64 + p * 16 + lr) * 768 + h * 384 + lk * 8);
  const unsigned short* pB = projB + h * 12 * 2048 + l * 8;

  f32x4 acc[4];
#pragma unroll
  for (int nt = 0; nt < 4; ++nt) acc[nt] = (f32x4){0.f, 0.f, 0.f, 0.f};

  for (int kt = 0; kt < 12; ++kt) {
    float4 a0 = *(const float4*)(pA);
    float4 a1 = *(const float4*)(pA + 4);
    pA += 32;
    const unsigned short* pb = pB + kt * 2048;
    short8v b0 = *(const short8v*)(pb);
    short8v b1 = *(const short8v*)(pb + 512);
    short8v b2 = *(const short8v*)(pb + 1024);
    short8v b3 = *(const short8v*)(pb + 1536);
    short8v av;
    av[0] = (short)f2bf(a0.x); av[1] = (short)f2bf(a0.y);
    av[2] = (short)f2bf(a0.z); av[3] = (short)f2bf(a0.w);
    av[4] = (short)f2bf(a1.x); av[5] = (short)f2bf(a1.y);
    av[6] = (short)f2bf(a1.z); av[7] = (short)f2bf(a1.w);
    acc[0] = __builtin_amdgcn_mfma_f32_16x16x32_bf16(av, b0, acc[0], 0, 0, 0);
    acc[1] = __builtin_amdgcn_mfma_f32_16x16x32_bf16(av, b1, acc[1], 0, 0, 0);
    acc[2] = __builtin_amdgcn_mfma_f32_16x16x32_bf16(av, b2, acc[2], 0, 0, 0);
    acc[3] = __builtin_amdgcn_mfma_f32_16x16x32_bf16(av, b3, acc[3], 0, 0, 0);
  }

  // ---- K-split combine: h=1 waves donate their partial acc via LDS ----
  if (h) {
#pragma unroll
    for (int nt = 0; nt < 4; ++nt)
#pragma unroll
      for (int i = 0; i < 4; ++i) xbuf[p][l][nt * 4 + i] = acc[nt][i];
  }
  __syncthreads();

  float th[4];
  if (!h) {
#pragma unroll
    for (int nt = 0; nt < 4; ++nt)
#pragma unroll
      for (int i = 0; i < 4; ++i) acc[nt][i] += xbuf[p][l][nt * 4 + i];

    // C layout: col = nt*16 + lr, row = lk*4 + i. Row-local group = 16 lanes.
    // ---- Phase 2a: expmap0 in-register ----
#pragma unroll
    for (int i = 0; i < 4; ++i) {
      float s = acc[0][i] * acc[0][i] + acc[1][i] * acc[1][i] +
                acc[2][i] * acc[2][i] + acc[3][i] * acc[3][i];
      s = gred16(s);
      float n = fmaxf(sqrtf(s), MIN_NORM);
      float t = tanhf(n);
      th[i] = fmaxf(t, MIN_NORM);  // xn = ||te||
      float sc = t / n;
#pragma unroll
      for (int nt = 0; nt < 4; ++nt) acc[nt][i] *= sc;  // te
    }

    // ---- te: C-layout -> A-frag layout via pair-private LDS (XOR-swizzled, G4) ----
    unsigned short* buf = teL[p];
#pragma unroll
    for (int i = 0; i < 4; ++i) {
      int row = lk * 4 + i;
      int sw = (row & 7) << 3;
#pragma unroll
      for (int nt = 0; nt < 4; ++nt) {
        int col = nt * 16 + lr;
        buf[row * 64 + (col ^ sw)] = f2bf(acc[nt][i]);
      }
    }
  }
  __syncthreads();

  if (!h) {
    // ---- Phase 2b: mx = te @ trans^T (K=64) ----
    const unsigned short* buf = teL[p];
    f32x4 acc2[4];
#pragma unroll
    for (int nt = 0; nt < 4; ++nt) acc2[nt] = (f32x4){0.f, 0.f, 0.f, 0.f};
    const unsigned short* pT = transB + l * 8;
#pragma unroll
    for (int kt = 0; kt < 2; ++kt) {
      short8v a2 = *(const short8v*)&buf[lr * 64 + ((kt * 32 + lk * 8) ^ ((lr & 7) << 3))];
      const unsigned short* pt = pT + kt * 2048;
      short8v c0 = *(const short8v*)(pt);
      short8v c1 = *(const short8v*)(pt + 512);
      short8v c2 = *(const short8v*)(pt + 1024);
      short8v c3 = *(const short8v*)(pt + 1536);
      acc2[0] = __builtin_amdgcn_mfma_f32_16x16x32_bf16(a2, c0, acc2[0], 0, 0, 0);
      acc2[1] = __builtin_amdgcn_mfma_f32_16x16x32_bf16(a2, c1, acc2[1], 0, 0, 0);
      acc2[2] = __builtin_amdgcn_mfma_f32_16x16x32_bf16(a2, c2, acc2[2], 0, 0, 0);
      acc2[3] = __builtin_amdgcn_mfma_f32_16x16x32_bf16(a2, c3, acc2[3], 0, 0, 0);
    }

    // ---- Phase 2c: mobius_matvec epilogue + dists, fully in-register ----
    float xp[4], xq[4];
#pragma unroll
    for (int nt = 0; nt < 4; ++nt) {
      xp[nt] = pos[nt * 16 + lr];
      xq[nt] = neg[nt * 16 + lr];
    }
    float x2p = wred64(xp[0] * xp[0] + xp[1] * xp[1] + xp[2] * xp[2] + xp[3] * xp[3]) * 0.25f;
    float x2n = wred64(xq[0] * xq[0] + xq[1] * xq[1] + xq[2] * xq[2] + xq[3] * xq[3]) * 0.25f;

    float distP = 0.f, distN = 0.f;
#pragma unroll
    for (int i = 0; i < 4; ++i) {
      float m0 = acc2[0][i], m1 = acc2[1][i], m2 = acc2[2][i], m3 = acc2[3][i];
      float s = gred16(m0 * m0 + m1 * m1 + m2 * m2 + m3 * m3);
      float mxn = fmaxf(sqrtf(s), MIN_NORM);
      float xn = th[i];
      float rs = tanhf(mxn / xn * artanh_c(xn)) / mxn;
      float r0 = rs * m0, r1 = rs * m1, r2 = rs * m2, r3 = rs * m3;
      float y2 = gred16(r0 * r0 + r1 * r1 + r2 * r2 + r3 * r3);
      float xyP = -gred16(xp[0] * r0 + xp[1] * r1 + xp[2] * r2 + xp[3] * r3);
      float xyN = -gred16(xq[0] * r0 + xq[1] * r1 + xq[2] * r2 + xq[3] * r3);
      {
        float A = 1.f + 2.f * xyP + y2, B = 1.f - x2p;
        float inv = 1.f / fmaxf(1.f + 2.f * xyP + x2p * y2, MIN_NORM);
        float v0 = (B * r0 - A * xp[0]) * inv, v1 = (B * r1 - A * xp[1]) * inv;
        float v2 = (B * r2 - A * xp[2]) * inv, v3 = (B * r3 - A * xp[3]) * inv;
        float nv = fmaxf(sqrtf(gred16(v0 * v0 + v1 * v1 + v2 * v2 + v3 * v3)), MIN_NORM);
        distP += 2.f * artanh_c(nv);
      }
      {
        float A = 1.f + 2.f * xyN + y2, B = 1.f - x2n;
        float inv = 1.f / fmaxf(1.f + 2.f * xyN + x2n * y2, MIN_NORM);
        float v0 = (B * r0 - A * xq[0]) * inv, v1 = (B * r1 - A * xq[1]) * inv;
        float v2 = (B * r2 - A * xq[2]) * inv, v3 = (B * r3 - A * xq[3]) * inv;
        float nv = fmaxf(sqrtf(gred16(v0 * v0 + v1 * v1 + v2 * v2 + v3 * v3)), MIN_NORM);
        distN += 2.f * artanh_c(nv);
      }
    }
    // Each group's dist is replicated on its 16 lanes: wred64/16 sums groups once.
    float tP = wred64(distP) * 0.0625f;
    float tN = wred64(distN) * 0.0625f;
    if (l == 0) { partial[p][0] = tP; partial[p][1] = tN; }
  }
  __syncthreads();
  if (tid == 0) {
    wsPart[bIdx * 2 + 0] = partial[0][0] + partial[1][0] + partial[2][0] + partial[3][0];
    wsPart[bIdx * 2 + 1] = partial[0][1] + partial[1][1] + partial[2][1] + partial[3][1];
  }
}

// Deterministic per-batch reduction: out[b][j] = sum over the batch's 16 blocks.
// Separate kernel => stream-ordered, no cross-XCD visibility hazard (G16).
__global__ __launch_bounds__(128) void poincare_reduce(const float* __restrict__ wsPart,
                                                       float* __restrict__ out) {
  int t = threadIdx.x;
  int b = t >> 1, j = t & 1;
  float s = 0.f;
#pragma unroll
  for (int i = 0; i < 16; ++i) s += wsPart[(b * 16 + i) * 2 + j];
  out[b * 2 + j] = s;
}

extern "C" void kernel_launch(void* const* d_in, const int* in_sizes, int n_in,
                              void* d_out, int out_size, void* d_ws, size_t ws_size,
                              hipStream_t stream) {
  const float* seq = (const float*)d_in[0];
  const float* proj = (const float*)d_in[1];
  const float* trans = (const float*)d_in[2];
  const float* pos = (const float*)d_in[3];
  const float* neg = (const float*)d_in[4];

  unsigned short* projB = (unsigned short*)d_ws;             // 49152 u16 = 98304 B
  unsigned short* transB = projB + 49152;                    // 4096 u16  = 8192 B
  float* wsPart = (float*)((char*)d_ws + 106496);            // 2048 f32  = 8192 B
  float* out = (float*)d_out;

  poincare_prep<<<208, 256, 0, stream>>>(proj, trans, projB, transB);
  poincare_main<<<1024, 512, 0, stream>>>(seq, projB, transB, pos, neg, wsPart);
  poincare_reduce<<<1, 128, 0, stream>>>(wsPart, out);
}